// Round 3
// baseline (1273.797 us; speedup 1.0000x reference)
//
#include <hip/hip_runtime.h>
#include <stdint.h>

#define K_DIM 4096
#define N_GROUPS 32

// fallback (fused_gemm) tile
#define BM 128
#define BN 128
#define BK 32

// 8-phase main GEMM tile
#define BM8 256
#define BN8 256
#define BK8 64
#define NT8 (K_DIM / BK8)   // 64 K-tiles

typedef __attribute__((ext_vector_type(4))) float f32x4;
typedef __attribute__((ext_vector_type(8))) __bf16 bf16x8;
typedef __attribute__((ext_vector_type(4))) unsigned int u32x4;

__device__ __forceinline__ unsigned short f2bf(float f) {
    union { float f; unsigned u; } c; c.f = f;
    unsigned u = c.u;
    u += 0x7FFFu + ((u >> 16) & 1u);   // RNE
    return (unsigned short)(u >> 16);
}

// ---------- prep 1: x fp32 -> bf16 ----------
__global__ __launch_bounds__(256) void cvt_x(const float* __restrict__ x,
                                             unsigned short* __restrict__ xb,
                                             int total) {
    int i = (blockIdx.x * 256 + threadIdx.x) * 8;
    if (i >= total) return;
    f32x4 a = *(const f32x4*)(x + i);
    f32x4 b = *(const f32x4*)(x + i + 4);
    union { unsigned short u[8]; uint4 v; } o;
    o.u[0] = f2bf(a.x); o.u[1] = f2bf(a.y); o.u[2] = f2bf(a.z); o.u[3] = f2bf(a.w);
    o.u[4] = f2bf(b.x); o.u[5] = f2bf(b.y); o.u[6] = f2bf(b.z); o.u[7] = f2bf(b.w);
    *(uint4*)(xb + i) = o.v;
}

// ---------- prep 2: packed int4 -> bf16 W[N][K] ----------
__global__ __launch_bounds__(256) void dequant_w(const int* __restrict__ wp,
                                                 const float* __restrict__ sc,
                                                 unsigned short* __restrict__ wd,
                                                 int total4) {
    int idx = blockIdx.x * 256 + threadIdx.x;   // int4 (4x int32) index
    if (idx >= total4) return;
    const int4 v = ((const int4*)wp)[idx];
    int flat = idx << 2;                 // int32 index
    int n = flat >> 11;                  // / (K/2 = 2048)
    int ci = flat & 2047;                // int32 col within row
    float s = sc[(n << 5) + (ci >> 6)];  // group = (2*ci)>>7 = ci>>6
    union { unsigned short u[8]; uint4 q; } o;
    int vv[4] = { v.x, v.y, v.z, v.w };
#pragma unroll
    for (int j = 0; j < 4; ++j) {
        int e = (vv[j] & 15) - 8;
        int d = ((vv[j] >> 4) & 15) - 8;
        o.u[2 * j]     = f2bf((float)e * s);
        o.u[2 * j + 1] = f2bf((float)d * s);
    }
    *(uint4*)(wd + ((size_t)n << 12) + (ci << 1)) = o.q;
}

// ---------- async global->LDS, 16B/lane ----------
__device__ __forceinline__ void gld16(const void* g, void* l) {
    __builtin_amdgcn_global_load_lds((__attribute__((address_space(1))) void*)g,
                                     (__attribute__((address_space(3))) void*)l,
                                     16, 0, 0);
}

// ---------- inline-asm ds_read_b128 with compile-time immediate offset ----------
template<int OFF>
__device__ __forceinline__ bf16x8 dsrT(unsigned a) {
    u32x4 d;
    asm volatile("ds_read_b128 %0, %1 offset:%2" : "=v"(d) : "v"(a), "n"(OFF));
    union { u32x4 u; bf16x8 b; } c; c.u = d;
    return c.b;
}

// read 4 consecutive 16-row fragments (frag stride 1024 B) at region offset o
#define RD4(dst, base, o) do {              \
    dst[0] = dsrT<(o)>(base);               \
    dst[1] = dsrT<(o) + 1024>(base);        \
    dst[2] = dsrT<(o) + 2048>(base);        \
    dst[3] = dsrT<(o) + 3072>(base); } while (0)

__device__ __forceinline__ unsigned lds_addr(const void* p) {
    return (unsigned)(uintptr_t)(__attribute__((address_space(3))) const void*)p;
}

#define MFMA_(va, vb, vc) __builtin_amdgcn_mfma_f32_16x16x32_bf16(va, vb, vc, 0, 0, 0)

// Stage one 16 KiB half-tile (256 rows x 32 k bf16): 2 x global_load_lds per wave.
#define STAGE(regbase, g, k) do {                                   \
    gld16((g) + (k), (regbase));                                    \
    gld16((g) + (size_t)128 * K_DIM + (k), (regbase) + 4096); } while (0)

// ---------- main GEMM: C[M,N] = A[M,K] * B[N,K]^T, 256x256 tile, 8-phase ----------
// LDS regions per buffer (16 KiB each, byte stride 16384):
//   0 = A k[0,32), 1 = A k[32,64), 2 = B k[0,32), 3 = B k[32,64).
// Register-load pipeline is ONE PHASE AHEAD: in body P we (a) lgkmcnt(0) for
// reads(P) issued last phase, (b) issue STAGE(P), (c) issue reads(P+1) so their
// LDS drain overlaps MFMA(P), (d) MFMA(P). Fragment register sets alternate
// (p1:a0,b0 / p2:a1,b0 / p3:a0,b1 / p4:a1,b1) so reads(P+1) never touch
// registers MFMA(P) uses. vmcnt(6) sits in phase 4 after STAGE issue and BEFORE
// the next-tile pre-reads (retires exactly all 4 half-tiles of T+1).
__global__ __launch_bounds__(512, 2) void gemm8p(const unsigned short* __restrict__ A,
                                                 const unsigned short* __restrict__ B,
                                                 float* __restrict__ C,
                                                 int M, int N) {
    __shared__ __align__(16) unsigned short lds[2][4][8192];   // 128 KiB

    const int tid  = threadIdx.x;
    const int wave = tid >> 6;          // 0..7
    const int lane = tid & 63;
    const int wm = wave >> 2;           // 0..1  (M half)
    const int wn = wave & 3;            // 0..3  (N quarter)

    // ---- bijective XCD swizzle (nwg = 1376, divisible by 8) ----
    const int nwg = gridDim.x;
    const int bid = blockIdx.x;
    const int q = nwg >> 3, r7 = nwg & 7;
    const int xcd = bid & 7, loc = bid >> 3;
    const int tile = (xcd < r7 ? xcd * (q + 1) : r7 * (q + 1) + (xcd - r7) * q) + loc;
    const int ntm = M / BM8;
    const int tm = tile % ntm;          // M-fast within an XCD chunk
    const int tn = tile / ntm;
    const int m0 = tm * BM8;
    const int n0 = tn * BN8;

    // ---- staging source (pre-swizzled global address; LDS dest stays linear) ----
    const int srow = lane >> 2;                                      // 0..15
    const int sx   = ((lane & 3) * 8) ^ (((lane >> 3) & 3) << 3);    // element col 0..31
    const unsigned short* Ag = A + (size_t)(m0 + wave * 16 + srow) * K_DIM + sx;
    const unsigned short* Bg = B + (size_t)(n0 + wave * 16 + srow) * K_DIM + sx;
    unsigned short* L  = &lds[0][0][0];
    unsigned short* Ld = L + wave * 512;         // wave chunk (1 KiB) inside a region

    // ---- fragment ds_read bases (swizzled on the read side) ----
    const int fr = lane & 15;
    const unsigned rofs = (unsigned)(fr * 64 + (((lane >> 4) * 16) ^ (((fr >> 1) & 3) << 4)));
    const unsigned ldsb = lds_addr(L);
    const unsigned aoff = ldsb + (unsigned)(wm * 8192) + rofs;            // A region 0, buf 0
    const unsigned boff = ldsb + 32768u + (unsigned)(wn * 4096) + rofs;   // B region 2, buf 0

    f32x4 acc[8][4] = {};
    bf16x8 a0[4], a1[4], b0[4], b1[4];

    // ---- prologue: T0 fully (8 loads), T1 partial (6 loads); vmcnt(6) completes T0 ----
    STAGE(Ld + 0 * 8192, Ag, 0);                // T0 A h0
    STAGE(Ld + 1 * 8192, Ag, 32);               // T0 A h1
    STAGE(Ld + 2 * 8192, Bg, 0);                // T0 B h0
    STAGE(Ld + 3 * 8192, Bg, 32);               // T0 B h1
    STAGE(Ld + 32768 + 2 * 8192, Bg, 64);       // T1 B h0 -> buf1
    STAGE(Ld + 32768 + 0 * 8192, Ag, 64);       // T1 A h0 -> buf1
    STAGE(Ld + 32768 + 3 * 8192, Bg, 96);       // T1 B h1 -> buf1
    asm volatile("s_waitcnt vmcnt(6)" ::: "memory");
    __builtin_amdgcn_s_barrier();

    // pre-issue reads(T0 p1): A ks0 m0-3 + B ks0 (buf0 is fully retired)
    RD4(a0, aoff, 0);
    RD4(b0, boff, 0);

    for (int T = 0; T < NT8; ++T) {
        const int buf = T & 1;
        const unsigned ab  = aoff + (unsigned)(buf * 65536);
        const unsigned bb  = boff + (unsigned)(buf * 65536);
        const unsigned abn = ab ^ 65536u;               // next buffer bases
        const unsigned bbn = bb ^ 65536u;
        unsigned short* Lc = Ld + buf * 32768;          // current buffer
        unsigned short* Ln = Ld + (buf ^ 1) * 32768;    // next buffer
        const int kn1 = ((T + 1) < NT8 ? (T + 1) : NT8 - 1) * BK8;  // clamp: tail stages garbage, never read
        const int kn2 = ((T + 2) < NT8 ? (T + 2) : NT8 - 1) * BK8;

        // ---------------- phase 1: MFMA(a0,b0) ks0 upper ----------------
        asm volatile("s_waitcnt lgkmcnt(0)" ::: "memory");   // reads(p1) ready
        __builtin_amdgcn_sched_barrier(0);
        STAGE(Ln + 1 * 8192, Ag, kn1 + 32);                  // (T+1) A h1
        RD4(a1, ab, 4096);                                   // reads(p2): A ks0 m4-7
        __builtin_amdgcn_sched_barrier(0);
        __builtin_amdgcn_s_setprio(1);
#pragma unroll
        for (int i = 0; i < 4; ++i)
#pragma unroll
            for (int j = 0; j < 4; ++j)
                acc[i][j] = MFMA_(a0[i], b0[j], acc[i][j]);
        __builtin_amdgcn_s_setprio(0);
        __builtin_amdgcn_s_barrier();

        // ---------------- phase 2: MFMA(a1,b0) ks0 lower ----------------
        asm volatile("s_waitcnt lgkmcnt(0)" ::: "memory");   // reads(p2) ready
        __builtin_amdgcn_sched_barrier(0);
        STAGE(Lc + 2 * 8192, Bg, kn2);                       // (T+2) B h0
        RD4(a0, ab, 16384);                                  // reads(p3): A ks1 m0-3
        RD4(b1, bb, 16384);                                  //            B ks1
        __builtin_amdgcn_sched_barrier(0);
        __builtin_amdgcn_s_setprio(1);
#pragma unroll
        for (int i = 0; i < 4; ++i)
#pragma unroll
            for (int j = 0; j < 4; ++j)
                acc[4 + i][j] = MFMA_(a1[i], b0[j], acc[4 + i][j]);
        __builtin_amdgcn_s_setprio(0);
        __builtin_amdgcn_s_barrier();

        // ---------------- phase 3: MFMA(a0,b1) ks1 upper ----------------
        asm volatile("s_waitcnt lgkmcnt(0)" ::: "memory");   // reads(p3) ready
        __builtin_amdgcn_sched_barrier(0);
        STAGE(Lc + 0 * 8192, Ag, kn2);                       // (T+2) A h0
        RD4(a1, ab, 16384 + 4096);                           // reads(p4): A ks1 m4-7
        __builtin_amdgcn_sched_barrier(0);
        __builtin_amdgcn_s_setprio(1);
#pragma unroll
        for (int i = 0; i < 4; ++i)
#pragma unroll
            for (int j = 0; j < 4; ++j)
                acc[i][j] = MFMA_(a0[i], b1[j], acc[i][j]);
        __builtin_amdgcn_s_setprio(0);
        __builtin_amdgcn_s_barrier();

        // ---------------- phase 4: MFMA(a1,b1) ks1 lower ----------------
        asm volatile("s_waitcnt lgkmcnt(0)" ::: "memory");   // reads(p4) ready
        __builtin_amdgcn_sched_barrier(0);
        STAGE(Lc + 3 * 8192, Bg, kn2 + 32);                  // (T+2) B h1
        asm volatile("s_waitcnt vmcnt(6)" ::: "memory");     // retire ALL of T+1 (next buf readable)
        RD4(a0, abn, 0);                                     // reads(next p1): A ks0 m0-3
        RD4(b0, bbn, 0);                                     //                 B ks0
        __builtin_amdgcn_sched_barrier(0);
        __builtin_amdgcn_s_setprio(1);
#pragma unroll
        for (int i = 0; i < 4; ++i)
#pragma unroll
            for (int j = 0; j < 4; ++j)
                acc[4 + i][j] = MFMA_(a1[i], b1[j], acc[4 + i][j]);
        __builtin_amdgcn_s_setprio(0);
        __builtin_amdgcn_s_barrier();
    }

    // ---- epilogue: C write (layout: col = lane&15, row = (lane>>4)*4 + reg) ----
    const int cr = (lane >> 4) * 4;
    const int cc = lane & 15;
#pragma unroll
    for (int i = 0; i < 8; ++i) {
#pragma unroll
        for (int j = 0; j < 4; ++j) {
            float* cp = C + (size_t)(m0 + wm * 128 + i * 16 + cr) * N + (n0 + wn * 64 + j * 16 + cc);
            cp[0]           = acc[i][j].x;
            cp[(size_t)N]   = acc[i][j].y;
            cp[(size_t)N*2] = acc[i][j].z;
            cp[(size_t)N*3] = acc[i][j].w;
        }
    }
}

// ---------- fallback: fused on-the-fly dequant GEMM (if ws too small) ----------
__global__ __launch_bounds__(256, 2) void fused_gemm(const float* __restrict__ X,
                                                     const int* __restrict__ Wp,
                                                     const float* __restrict__ Sc,
                                                     float* __restrict__ C,
                                                     int M, int N) {
    __shared__ __align__(16) unsigned short As[BM * BK];
    __shared__ __align__(16) unsigned short Bs[BN * BK];

    const int tid  = threadIdx.x;
    const int wave = tid >> 6;
    const int lane = tid & 63;
    const int m0 = blockIdx.y * BM;
    const int n0 = blockIdx.x * BN;
    const int wm = (wave >> 1) * 64;
    const int wn = (wave & 1) * 64;

    const int fr = lane & 15;
    const int fk = (lane >> 4) * 8;

    f32x4 acc[4][4] = {};

    for (int k0 = 0; k0 < K_DIM; k0 += BK) {
        __syncthreads();
#pragma unroll
        for (int j = 0; j < 4; ++j) {
            int f = tid + 256 * j;
            int row = f >> 3, c4 = f & 7;
            f32x4 a = *(const f32x4*)(X + (size_t)(m0 + row) * K_DIM + k0 + c4 * 4);
            union { unsigned short u[4]; uint2 q; } o;
            o.u[0] = f2bf(a.x); o.u[1] = f2bf(a.y); o.u[2] = f2bf(a.z); o.u[3] = f2bf(a.w);
            *(uint2*)(As + row * BK + c4 * 4) = o.q;
        }
#pragma unroll
        for (int j = 0; j < 2; ++j) {
            int g = tid + 256 * j;
            int row = g >> 2, c4 = g & 3;
            const int4 v = *(const int4*)(Wp + (size_t)(n0 + row) * (K_DIM / 2) + (k0 >> 1) + c4 * 4);
            float s = Sc[(n0 + row) * N_GROUPS + (k0 >> 7)];
            union { unsigned short u[8]; uint4 q; } o;
            int vv[4] = { v.x, v.y, v.z, v.w };
#pragma unroll
            for (int t = 0; t < 4; ++t) {
                o.u[2 * t]     = f2bf((float)((vv[t] & 15) - 8) * s);
                o.u[2 * t + 1] = f2bf((float)(((vv[t] >> 4) & 15) - 8) * s);
            }
            *(uint4*)(Bs + row * BK + c4 * 8) = o.q;
        }
        __syncthreads();

        bf16x8 af[4], bf[4];
#pragma unroll
        for (int i = 0; i < 4; ++i) {
            af[i] = *(const bf16x8*)(As + (wm + i * 16 + fr) * BK + fk);
            bf[i] = *(const bf16x8*)(Bs + (wn + i * 16 + fr) * BK + fk);
        }
#pragma unroll
        for (int i = 0; i < 4; ++i)
#pragma unroll
            for (int j = 0; j < 4; ++j)
                acc[i][j] = __builtin_amdgcn_mfma_f32_16x16x32_bf16(af[i], bf[j], acc[i][j], 0, 0, 0);
    }

    const int cr = (lane >> 4) * 4;
    const int cc = lane & 15;
#pragma unroll
    for (int i = 0; i < 4; ++i) {
#pragma unroll
        for (int j = 0; j < 4; ++j) {
            float* cp = C + (size_t)(m0 + wm + i * 16 + cr) * N + (n0 + wn + j * 16 + cc);
            cp[0]           = acc[i][j].x;
            cp[(size_t)N]   = acc[i][j].y;
            cp[(size_t)N*2] = acc[i][j].z;
            cp[(size_t)N*3] = acc[i][j].w;
        }
    }
}

extern "C" void kernel_launch(void* const* d_in, const int* in_sizes, int n_in,
                              void* d_out, int out_size, void* d_ws, size_t ws_size,
                              hipStream_t stream) {
    const float* x  = (const float*)d_in[0];
    const int*   wp = (const int*)d_in[1];
    const float* sc = (const float*)d_in[2];
    float* out = (float*)d_out;

    const int M = in_sizes[0] / K_DIM;       // 8192
    const int N = in_sizes[2] / N_GROUPS;    // 11008

    const size_t xb_bytes = (size_t)M * K_DIM * 2;   // 67 MB
    const size_t wd_bytes = (size_t)N * K_DIM * 2;   // 90 MB

    const bool div256 = (M % BM8 == 0) && (N % BN8 == 0);

    if (ws_size >= xb_bytes + wd_bytes && div256) {
        unsigned short* xb = (unsigned short*)d_ws;
        unsigned short* wd = (unsigned short*)((char*)d_ws + xb_bytes);
        int xtot = M * K_DIM;
        cvt_x<<<xtot / (256 * 8), 256, 0, stream>>>(x, xb, xtot);
        int wtot4 = N * (K_DIM / 2) / 4;
        dequant_w<<<(wtot4 + 255) / 256, 256, 0, stream>>>(wp, sc, wd, wtot4);
        gemm8p<<<(M / BM8) * (N / BN8), 512, 0, stream>>>(xb, wd, out, M, N);
    } else {
        dim3 grid(N / BN, M / BM);
        fused_gemm<<<grid, 256, 0, stream>>>(x, wp, sc, out, M, N);
    }
}

// Round 4
// 1111.347 us; speedup vs baseline: 1.1462x; 1.1462x over previous
//
#include <hip/hip_runtime.h>
#include <stdint.h>

#define K_DIM 4096
#define N_GROUPS 32

// fallback (fused_gemm) tile
#define BM 128
#define BN 128
#define BK 32

// 8-phase main GEMM tile
#define BM8 256
#define BN8 256
#define BK8 64
#define NT8 (K_DIM / BK8)   // 64 K-tiles

typedef __attribute__((ext_vector_type(4))) float f32x4;
typedef __attribute__((ext_vector_type(8))) __bf16 bf16x8;
typedef __attribute__((ext_vector_type(4))) unsigned int u32x4;

__device__ __forceinline__ unsigned short f2bf(float f) {
    union { float f; unsigned u; } c; c.f = f;
    unsigned u = c.u;
    u += 0x7FFFu + ((u >> 16) & 1u);   // RNE
    return (unsigned short)(u >> 16);
}

// ---------- prep 1: x fp32 -> bf16 ----------
// nt loads: x is read exactly once -> don't let it evict A/B from L3.
__global__ __launch_bounds__(256) void cvt_x(const float* __restrict__ x,
                                             unsigned short* __restrict__ xb,
                                             int total) {
    int i = (blockIdx.x * 256 + threadIdx.x) * 8;
    if (i >= total) return;
    f32x4 a = __builtin_nontemporal_load((const f32x4*)(x + i));
    f32x4 b = __builtin_nontemporal_load((const f32x4*)(x + i + 4));
    union { unsigned short u[8]; uint4 v; } o;
    o.u[0] = f2bf(a.x); o.u[1] = f2bf(a.y); o.u[2] = f2bf(a.z); o.u[3] = f2bf(a.w);
    o.u[4] = f2bf(b.x); o.u[5] = f2bf(b.y); o.u[6] = f2bf(b.z); o.u[7] = f2bf(b.w);
    *(uint4*)(xb + i) = o.v;   // cached: gemm re-reads xb many times
}

// ---------- prep 2: packed int4 -> bf16 W[N][K] ----------
__global__ __launch_bounds__(256) void dequant_w(const int* __restrict__ wp,
                                                 const float* __restrict__ sc,
                                                 unsigned short* __restrict__ wd,
                                                 int total4) {
    int idx = blockIdx.x * 256 + threadIdx.x;   // int4 (4x int32) index
    if (idx >= total4) return;
    const u32x4 v = __builtin_nontemporal_load((const u32x4*)wp + idx);  // read-once
    int flat = idx << 2;                 // int32 index
    int n = flat >> 11;                  // / (K/2 = 2048)
    int ci = flat & 2047;                // int32 col within row
    float s = sc[(n << 5) + (ci >> 6)];  // group = (2*ci)>>7 = ci>>6
    union { unsigned short u[8]; uint4 q; } o;
#pragma unroll
    for (int j = 0; j < 4; ++j) {
        int vv = (int)v[j];
        int e = (vv & 15) - 8;
        int d = ((vv >> 4) & 15) - 8;
        o.u[2 * j]     = f2bf((float)e * s);
        o.u[2 * j + 1] = f2bf((float)d * s);
    }
    *(uint4*)(wd + ((size_t)n << 12) + (ci << 1)) = o.q;   // cached: re-read by gemm
}

// ---------- async global->LDS, 16B/lane ----------
__device__ __forceinline__ void gld16(const void* g, void* l) {
    __builtin_amdgcn_global_load_lds((__attribute__((address_space(1))) void*)g,
                                     (__attribute__((address_space(3))) void*)l,
                                     16, 0, 0);
}

// ---------- inline-asm ds_read_b128 with compile-time immediate offset ----------
template<int OFF>
__device__ __forceinline__ bf16x8 dsrT(unsigned a) {
    u32x4 d;
    asm volatile("ds_read_b128 %0, %1 offset:%2" : "=v"(d) : "v"(a), "n"(OFF));
    union { u32x4 u; bf16x8 b; } c; c.u = d;
    return c.b;
}

// read 4 consecutive 16-row fragments (frag stride 1024 B) at region offset o
#define RD4(dst, base, o) do {              \
    dst[0] = dsrT<(o)>(base);               \
    dst[1] = dsrT<(o) + 1024>(base);        \
    dst[2] = dsrT<(o) + 2048>(base);        \
    dst[3] = dsrT<(o) + 3072>(base); } while (0)

__device__ __forceinline__ unsigned lds_addr(const void* p) {
    return (unsigned)(uintptr_t)(__attribute__((address_space(3))) const void*)p;
}

#define MFMA_(va, vb, vc) __builtin_amdgcn_mfma_f32_16x16x32_bf16(va, vb, vc, 0, 0, 0)

// Stage one 16 KiB half-tile (256 rows x 32 k bf16): 2 x global_load_lds per wave.
#define STAGE(regbase, g, k) do {                                   \
    gld16((g) + (k), (regbase));                                    \
    gld16((g) + (size_t)128 * K_DIM + (k), (regbase) + 4096); } while (0)

// ---------- main GEMM: C[M,N] = A[M,K] * B[N,K]^T, 256x256 tile, 8-phase ----------
// LDS regions per buffer (16 KiB each, byte stride 16384):
//   0 = A k[0,32), 1 = A k[32,64), 2 = B k[0,32), 3 = B k[32,64).
// Register-load pipeline is ONE PHASE AHEAD: in body P we (a) lgkmcnt(0) for
// reads(P) issued last phase, (b) issue STAGE(P), (c) issue reads(P+1) so their
// LDS drain overlaps MFMA(P), (d) MFMA(P). Fragment register sets alternate
// (p1:a0,b0 / p2:a1,b0 / p3:a0,b1 / p4:a1,b1) so reads(P+1) never touch
// registers MFMA(P) uses. vmcnt(6) sits in phase 4 after STAGE issue and BEFORE
// the next-tile pre-reads (retires exactly all 4 half-tiles of T+1).
// C epilogue uses NON-TEMPORAL stores: C (352 MB/dispatch) otherwise thrashes
// L3 and evicts A/B (157 MB), turning A-panel re-reads into HBM fetches
// (measured FETCH 1.6 GB = 10x input size) that lengthen the vmcnt supply wait.
__global__ __launch_bounds__(512, 2) void gemm8p(const unsigned short* __restrict__ A,
                                                 const unsigned short* __restrict__ B,
                                                 float* __restrict__ C,
                                                 int M, int N) {
    __shared__ __align__(16) unsigned short lds[2][4][8192];   // 128 KiB

    const int tid  = threadIdx.x;
    const int wave = tid >> 6;          // 0..7
    const int lane = tid & 63;
    const int wm = wave >> 2;           // 0..1  (M half)
    const int wn = wave & 3;            // 0..3  (N quarter)

    // ---- bijective XCD swizzle (nwg = 1376, divisible by 8) ----
    const int nwg = gridDim.x;
    const int bid = blockIdx.x;
    const int q = nwg >> 3, r7 = nwg & 7;
    const int xcd = bid & 7, loc = bid >> 3;
    const int tile = (xcd < r7 ? xcd * (q + 1) : r7 * (q + 1) + (xcd - r7) * q) + loc;
    const int ntm = M / BM8;
    const int tm = tile % ntm;          // M-fast within an XCD chunk
    const int tn = tile / ntm;
    const int m0 = tm * BM8;
    const int n0 = tn * BN8;

    // ---- staging source (pre-swizzled global address; LDS dest stays linear) ----
    const int srow = lane >> 2;                                      // 0..15
    const int sx   = ((lane & 3) * 8) ^ (((lane >> 3) & 3) << 3);    // element col 0..31
    const unsigned short* Ag = A + (size_t)(m0 + wave * 16 + srow) * K_DIM + sx;
    const unsigned short* Bg = B + (size_t)(n0 + wave * 16 + srow) * K_DIM + sx;
    unsigned short* L  = &lds[0][0][0];
    unsigned short* Ld = L + wave * 512;         // wave chunk (1 KiB) inside a region

    // ---- fragment ds_read bases (swizzled on the read side) ----
    const int fr = lane & 15;
    const unsigned rofs = (unsigned)(fr * 64 + (((lane >> 4) * 16) ^ (((fr >> 1) & 3) << 4)));
    const unsigned ldsb = lds_addr(L);
    const unsigned aoff = ldsb + (unsigned)(wm * 8192) + rofs;            // A region 0, buf 0
    const unsigned boff = ldsb + 32768u + (unsigned)(wn * 4096) + rofs;   // B region 2, buf 0

    f32x4 acc[8][4] = {};
    bf16x8 a0[4], a1[4], b0[4], b1[4];

    // ---- prologue: T0 fully (8 loads), T1 partial (6 loads); vmcnt(6) completes T0 ----
    STAGE(Ld + 0 * 8192, Ag, 0);                // T0 A h0
    STAGE(Ld + 1 * 8192, Ag, 32);               // T0 A h1
    STAGE(Ld + 2 * 8192, Bg, 0);                // T0 B h0
    STAGE(Ld + 3 * 8192, Bg, 32);               // T0 B h1
    STAGE(Ld + 32768 + 2 * 8192, Bg, 64);       // T1 B h0 -> buf1
    STAGE(Ld + 32768 + 0 * 8192, Ag, 64);       // T1 A h0 -> buf1
    STAGE(Ld + 32768 + 3 * 8192, Bg, 96);       // T1 B h1 -> buf1
    asm volatile("s_waitcnt vmcnt(6)" ::: "memory");
    __builtin_amdgcn_s_barrier();

    // pre-issue reads(T0 p1): A ks0 m0-3 + B ks0 (buf0 is fully retired)
    RD4(a0, aoff, 0);
    RD4(b0, boff, 0);

    for (int T = 0; T < NT8; ++T) {
        const int buf = T & 1;
        const unsigned ab  = aoff + (unsigned)(buf * 65536);
        const unsigned bb  = boff + (unsigned)(buf * 65536);
        const unsigned abn = ab ^ 65536u;               // next buffer bases
        const unsigned bbn = bb ^ 65536u;
        unsigned short* Lc = Ld + buf * 32768;          // current buffer
        unsigned short* Ln = Ld + (buf ^ 1) * 32768;    // next buffer
        const int kn1 = ((T + 1) < NT8 ? (T + 1) : NT8 - 1) * BK8;  // clamp: tail stages garbage, never read
        const int kn2 = ((T + 2) < NT8 ? (T + 2) : NT8 - 1) * BK8;

        // ---------------- phase 1: MFMA(a0,b0) ks0 upper ----------------
        asm volatile("s_waitcnt lgkmcnt(0)" ::: "memory");   // reads(p1) ready
        __builtin_amdgcn_sched_barrier(0);
        STAGE(Ln + 1 * 8192, Ag, kn1 + 32);                  // (T+1) A h1
        RD4(a1, ab, 4096);                                   // reads(p2): A ks0 m4-7
        __builtin_amdgcn_sched_barrier(0);
        __builtin_amdgcn_s_setprio(1);
#pragma unroll
        for (int i = 0; i < 4; ++i)
#pragma unroll
            for (int j = 0; j < 4; ++j)
                acc[i][j] = MFMA_(a0[i], b0[j], acc[i][j]);
        __builtin_amdgcn_s_setprio(0);
        __builtin_amdgcn_s_barrier();

        // ---------------- phase 2: MFMA(a1,b0) ks0 lower ----------------
        asm volatile("s_waitcnt lgkmcnt(0)" ::: "memory");   // reads(p2) ready
        __builtin_amdgcn_sched_barrier(0);
        STAGE(Lc + 2 * 8192, Bg, kn2);                       // (T+2) B h0
        RD4(a0, ab, 16384);                                  // reads(p3): A ks1 m0-3
        RD4(b1, bb, 16384);                                  //            B ks1
        __builtin_amdgcn_sched_barrier(0);
        __builtin_amdgcn_s_setprio(1);
#pragma unroll
        for (int i = 0; i < 4; ++i)
#pragma unroll
            for (int j = 0; j < 4; ++j)
                acc[4 + i][j] = MFMA_(a1[i], b0[j], acc[4 + i][j]);
        __builtin_amdgcn_s_setprio(0);
        __builtin_amdgcn_s_barrier();

        // ---------------- phase 3: MFMA(a0,b1) ks1 upper ----------------
        asm volatile("s_waitcnt lgkmcnt(0)" ::: "memory");   // reads(p3) ready
        __builtin_amdgcn_sched_barrier(0);
        STAGE(Lc + 0 * 8192, Ag, kn2);                       // (T+2) A h0
        RD4(a1, ab, 16384 + 4096);                           // reads(p4): A ks1 m4-7
        __builtin_amdgcn_sched_barrier(0);
        __builtin_amdgcn_s_setprio(1);
#pragma unroll
        for (int i = 0; i < 4; ++i)
#pragma unroll
            for (int j = 0; j < 4; ++j)
                acc[i][j] = MFMA_(a0[i], b1[j], acc[i][j]);
        __builtin_amdgcn_s_setprio(0);
        __builtin_amdgcn_s_barrier();

        // ---------------- phase 4: MFMA(a1,b1) ks1 lower ----------------
        asm volatile("s_waitcnt lgkmcnt(0)" ::: "memory");   // reads(p4) ready
        __builtin_amdgcn_sched_barrier(0);
        STAGE(Lc + 3 * 8192, Bg, kn2 + 32);                  // (T+2) B h1
        asm volatile("s_waitcnt vmcnt(6)" ::: "memory");     // retire ALL of T+1 (next buf readable)
        RD4(a0, abn, 0);                                     // reads(next p1): A ks0 m0-3
        RD4(b0, bbn, 0);                                     //                 B ks0
        __builtin_amdgcn_sched_barrier(0);
        __builtin_amdgcn_s_setprio(1);
#pragma unroll
        for (int i = 0; i < 4; ++i)
#pragma unroll
            for (int j = 0; j < 4; ++j)
                acc[4 + i][j] = MFMA_(a1[i], b1[j], acc[4 + i][j]);
        __builtin_amdgcn_s_setprio(0);
        __builtin_amdgcn_s_barrier();
    }

    // ---- epilogue: NON-TEMPORAL C write (col = lane&15, row = (lane>>4)*4 + reg) ----
    const int cr = (lane >> 4) * 4;
    const int cc = lane & 15;
#pragma unroll
    for (int i = 0; i < 8; ++i) {
#pragma unroll
        for (int j = 0; j < 4; ++j) {
            float* cp = C + (size_t)(m0 + wm * 128 + i * 16 + cr) * N + (n0 + wn * 64 + j * 16 + cc);
            __builtin_nontemporal_store(acc[i][j].x, cp);
            __builtin_nontemporal_store(acc[i][j].y, cp + (size_t)N);
            __builtin_nontemporal_store(acc[i][j].z, cp + (size_t)N * 2);
            __builtin_nontemporal_store(acc[i][j].w, cp + (size_t)N * 3);
        }
    }
}

// ---------- fallback: fused on-the-fly dequant GEMM (if ws too small) ----------
__global__ __launch_bounds__(256, 2) void fused_gemm(const float* __restrict__ X,
                                                     const int* __restrict__ Wp,
                                                     const float* __restrict__ Sc,
                                                     float* __restrict__ C,
                                                     int M, int N) {
    __shared__ __align__(16) unsigned short As[BM * BK];
    __shared__ __align__(16) unsigned short Bs[BN * BK];

    const int tid  = threadIdx.x;
    const int wave = tid >> 6;
    const int lane = tid & 63;
    const int m0 = blockIdx.y * BM;
    const int n0 = blockIdx.x * BN;
    const int wm = (wave >> 1) * 64;
    const int wn = (wave & 1) * 64;

    const int fr = lane & 15;
    const int fk = (lane >> 4) * 8;

    f32x4 acc[4][4] = {};

    for (int k0 = 0; k0 < K_DIM; k0 += BK) {
        __syncthreads();
#pragma unroll
        for (int j = 0; j < 4; ++j) {
            int f = tid + 256 * j;
            int row = f >> 3, c4 = f & 7;
            f32x4 a = *(const f32x4*)(X + (size_t)(m0 + row) * K_DIM + k0 + c4 * 4);
            union { unsigned short u[4]; uint2 q; } o;
            o.u[0] = f2bf(a.x); o.u[1] = f2bf(a.y); o.u[2] = f2bf(a.z); o.u[3] = f2bf(a.w);
            *(uint2*)(As + row * BK + c4 * 4) = o.q;
        }
#pragma unroll
        for (int j = 0; j < 2; ++j) {
            int g = tid + 256 * j;
            int row = g >> 2, c4 = g & 3;
            const int4 v = *(const int4*)(Wp + (size_t)(n0 + row) * (K_DIM / 2) + (k0 >> 1) + c4 * 4);
            float s = Sc[(n0 + row) * N_GROUPS + (k0 >> 7)];
            union { unsigned short u[8]; uint4 q; } o;
            int vv[4] = { v.x, v.y, v.z, v.w };
#pragma unroll
            for (int t = 0; t < 4; ++t) {
                o.u[2 * t]     = f2bf((float)((vv[t] & 15) - 8) * s);
                o.u[2 * t + 1] = f2bf((float)(((vv[t] >> 4) & 15) - 8) * s);
            }
            *(uint4*)(Bs + row * BK + c4 * 8) = o.q;
        }
        __syncthreads();

        bf16x8 af[4], bf[4];
#pragma unroll
        for (int i = 0; i < 4; ++i) {
            af[i] = *(const bf16x8*)(As + (wm + i * 16 + fr) * BK + fk);
            bf[i] = *(const bf16x8*)(Bs + (wn + i * 16 + fr) * BK + fk);
        }
#pragma unroll
        for (int i = 0; i < 4; ++i)
#pragma unroll
            for (int j = 0; j < 4; ++j)
                acc[i][j] = __builtin_amdgcn_mfma_f32_16x16x32_bf16(af[i], bf[j], acc[i][j], 0, 0, 0);
    }

    const int cr = (lane >> 4) * 4;
    const int cc = lane & 15;
#pragma unroll
    for (int i = 0; i < 4; ++i) {
#pragma unroll
        for (int j = 0; j < 4; ++j) {
            float* cp = C + (size_t)(m0 + wm + i * 16 + cr) * N + (n0 + wn + j * 16 + cc);
            cp[0]           = acc[i][j].x;
            cp[(size_t)N]   = acc[i][j].y;
            cp[(size_t)N*2] = acc[i][j].z;
            cp[(size_t)N*3] = acc[i][j].w;
        }
    }
}

extern "C" void kernel_launch(void* const* d_in, const int* in_sizes, int n_in,
                              void* d_out, int out_size, void* d_ws, size_t ws_size,
                              hipStream_t stream) {
    const float* x  = (const float*)d_in[0];
    const int*   wp = (const int*)d_in[1];
    const float* sc = (const float*)d_in[2];
    float* out = (float*)d_out;

    const int M = in_sizes[0] / K_DIM;       // 8192
    const int N = in_sizes[2] / N_GROUPS;    // 11008

    const size_t xb_bytes = (size_t)M * K_DIM * 2;   // 67 MB
    const size_t wd_bytes = (size_t)N * K_DIM * 2;   // 90 MB

    const bool div256 = (M % BM8 == 0) && (N % BN8 == 0);

    if (ws_size >= xb_bytes + wd_bytes && div256) {
        unsigned short* xb = (unsigned short*)d_ws;
        unsigned short* wd = (unsigned short*)((char*)d_ws + xb_bytes);
        int xtot = M * K_DIM;
        cvt_x<<<xtot / (256 * 8), 256, 0, stream>>>(x, xb, xtot);
        int wtot4 = N * (K_DIM / 2) / 4;
        dequant_w<<<(wtot4 + 255) / 256, 256, 0, stream>>>(wp, sc, wd, wtot4);
        gemm8p<<<(M / BM8) * (N / BN8), 512, 0, stream>>>(xb, wd, out, M, N);
    } else {
        dim3 grid(N / BN, M / BM);
        fused_gemm<<<grid, 256, 0, stream>>>(x, wp, sc, out, M, N);
    }
}

// Round 5
// 1086.314 us; speedup vs baseline: 1.1726x; 1.0230x over previous
//
#include <hip/hip_runtime.h>
#include <stdint.h>

#define K_DIM 4096
#define N_GROUPS 32

// fallback (fused_gemm) tile
#define BM 128
#define BN 128
#define BK 32

// 8-phase main GEMM tile
#define BM8 256
#define BN8 256
#define BK8 64
#define NT8 (K_DIM / BK8)   // 64 K-tiles

typedef __attribute__((ext_vector_type(4))) float f32x4;
typedef __attribute__((ext_vector_type(8))) __bf16 bf16x8;
typedef __attribute__((ext_vector_type(4))) unsigned int u32x4;

__device__ __forceinline__ unsigned short f2bf(float f) {
    union { float f; unsigned u; } c; c.f = f;
    unsigned u = c.u;
    u += 0x7FFFu + ((u >> 16) & 1u);   // RNE
    return (unsigned short)(u >> 16);
}

// ---------- prep 1: x fp32 -> bf16 ----------
// nt loads: x is read exactly once -> don't let it evict A/B from caches.
__global__ __launch_bounds__(256) void cvt_x(const float* __restrict__ x,
                                             unsigned short* __restrict__ xb,
                                             int total) {
    int i = (blockIdx.x * 256 + threadIdx.x) * 8;
    if (i >= total) return;
    f32x4 a = __builtin_nontemporal_load((const f32x4*)(x + i));
    f32x4 b = __builtin_nontemporal_load((const f32x4*)(x + i + 4));
    union { unsigned short u[8]; uint4 v; } o;
    o.u[0] = f2bf(a.x); o.u[1] = f2bf(a.y); o.u[2] = f2bf(a.z); o.u[3] = f2bf(a.w);
    o.u[4] = f2bf(b.x); o.u[5] = f2bf(b.y); o.u[6] = f2bf(b.z); o.u[7] = f2bf(b.w);
    *(uint4*)(xb + i) = o.v;   // cached: gemm re-reads xb many times
}

// ---------- prep 2: packed int4 -> bf16 W[N][K] ----------
__global__ __launch_bounds__(256) void dequant_w(const int* __restrict__ wp,
                                                 const float* __restrict__ sc,
                                                 unsigned short* __restrict__ wd,
                                                 int total4) {
    int idx = blockIdx.x * 256 + threadIdx.x;   // int4 (4x int32) index
    if (idx >= total4) return;
    const u32x4 v = __builtin_nontemporal_load((const u32x4*)wp + idx);  // read-once
    int flat = idx << 2;                 // int32 index
    int n = flat >> 11;                  // / (K/2 = 2048)
    int ci = flat & 2047;                // int32 col within row
    float s = sc[(n << 5) + (ci >> 6)];  // group = (2*ci)>>7 = ci>>6
    union { unsigned short u[8]; uint4 q; } o;
#pragma unroll
    for (int j = 0; j < 4; ++j) {
        int vv = (int)v[j];
        int e = (vv & 15) - 8;
        int d = ((vv >> 4) & 15) - 8;
        o.u[2 * j]     = f2bf((float)e * s);
        o.u[2 * j + 1] = f2bf((float)d * s);
    }
    *(uint4*)(wd + ((size_t)n << 12) + (ci << 1)) = o.q;   // cached: re-read by gemm
}

// ---------- async global->LDS, 16B/lane ----------
__device__ __forceinline__ void gld16(const void* g, void* l) {
    __builtin_amdgcn_global_load_lds((__attribute__((address_space(1))) void*)g,
                                     (__attribute__((address_space(3))) void*)l,
                                     16, 0, 0);
}

// ---------- inline-asm ds_read_b128 with compile-time immediate offset ----------
template<int OFF>
__device__ __forceinline__ bf16x8 dsrT(unsigned a) {
    u32x4 d;
    asm volatile("ds_read_b128 %0, %1 offset:%2" : "=v"(d) : "v"(a), "n"(OFF));
    union { u32x4 u; bf16x8 b; } c; c.u = d;
    return c.b;
}

// read 4 consecutive 16-row fragments (frag stride 1024 B) at region offset o
#define RD4(dst, base, o) do {              \
    dst[0] = dsrT<(o)>(base);               \
    dst[1] = dsrT<(o) + 1024>(base);        \
    dst[2] = dsrT<(o) + 2048>(base);        \
    dst[3] = dsrT<(o) + 3072>(base); } while (0)

__device__ __forceinline__ unsigned lds_addr(const void* p) {
    return (unsigned)(uintptr_t)(__attribute__((address_space(3))) const void*)p;
}

#define MFMA_(va, vb, vc) __builtin_amdgcn_mfma_f32_16x16x32_bf16(va, vb, vc, 0, 0, 0)

// Stage one 16 KiB half-tile (256 rows x 32 k bf16): 2 x global_load_lds per wave.
#define STAGE(regbase, g, k) do {                                   \
    gld16((g) + (k), (regbase));                                    \
    gld16((g) + (size_t)128 * K_DIM + (k), (regbase) + 4096); } while (0)

// ---------- main GEMM: C[M,N] = A[M,K] * B[N,K]^T, 256x256 tile, 8-phase ----------
// LDS regions per buffer (16 KiB each, byte stride 16384):
//   0 = A k[0,32), 1 = A k[32,64), 2 = B k[0,32), 3 = B k[32,64).
// Register-load pipeline is ONE PHASE AHEAD: in body P we (a) lgkmcnt(0) for
// reads(P) issued last phase, (b) issue STAGE(P), (c) issue reads(P+1) so their
// LDS drain overlaps MFMA(P), (d) MFMA(P). Fragment register sets alternate
// (p1:a0,b0 / p2:a1,b0 / p3:a0,b1 / p4:a1,b1) so reads(P+1) never touch
// registers MFMA(P) uses. vmcnt(6) sits in phase 4 after STAGE issue and BEFORE
// the next-tile pre-reads (retires exactly all 4 half-tiles of T+1).
// C epilogue uses NON-TEMPORAL stores (no L2 write-allocate pressure).
// Tile->block mapping: rectangular XCD chunks (see below) so the 32 co-resident
// blocks of an XCD share staging slices in its private L2.
__global__ __launch_bounds__(512, 2) void gemm8p(const unsigned short* __restrict__ A,
                                                 const unsigned short* __restrict__ B,
                                                 float* __restrict__ C,
                                                 int M, int N) {
    __shared__ __align__(16) unsigned short lds[2][4][8192];   // 128 KiB

    const int tid  = threadIdx.x;
    const int wave = tid >> 6;          // 0..7
    const int lane = tid & 63;
    const int wm = wave >> 2;           // 0..1  (M half)
    const int wn = wave & 3;            // 0..3  (N quarter)

    // ---- tile mapping ----
    // Rectangular XCD mapping: XCD x owns M-rows [x*R, (x+1)*R) x all N-cols.
    // With 1 block/CU (128 KiB LDS), the 32 co-resident blocks of an XCD are
    // consecutive loc indices; ordering them as an R x (32/R) rectangle makes
    // each K-slice's staging working set R*32KB (A, shared 32/R-way) +
    // (32/R)*32KB (B, shared R-way) = 384 KB << 4 MiB L2 -> ~80% of staging
    // becomes XCD-L2 hits instead of L3/HBM (measured FETCH 1.56 GB = A-sweep).
    const int ntm = M / BM8;            // 32
    const int bid = blockIdx.x;
    int tm, tn;
    if ((ntm & 7) == 0) {
        const int R  = ntm >> 3;        // M-rows per XCD (4)
        const int xc = bid & 7;         // XCD (dispatch round-robins XCDs)
        const int loc = bid >> 3;       // 0 .. ntm*ntn/8 - 1 within XCD
        const int r  = loc >> 5;        // rectangle (generation) index
        const int w  = loc & 31;        // position within rectangle
        tm = xc * R + (w % R);
        tn = r * (32 / R) + (w / R);    // last rectangle is partial; still in range
    } else {
        // fallback: bijective chunked swizzle
        const int nwg = gridDim.x;
        const int q = nwg >> 3, r7 = nwg & 7;
        const int xcd = bid & 7, loc = bid >> 3;
        const int tile = (xcd < r7 ? xcd * (q + 1) : r7 * (q + 1) + (xcd - r7) * q) + loc;
        tm = tile % ntm;
        tn = tile / ntm;
    }
    const int m0 = tm * BM8;
    const int n0 = tn * BN8;

    // ---- staging source (pre-swizzled global address; LDS dest stays linear) ----
    const int srow = lane >> 2;                                      // 0..15
    const int sx   = ((lane & 3) * 8) ^ (((lane >> 3) & 3) << 3);    // element col 0..31
    const unsigned short* Ag = A + (size_t)(m0 + wave * 16 + srow) * K_DIM + sx;
    const unsigned short* Bg = B + (size_t)(n0 + wave * 16 + srow) * K_DIM + sx;
    unsigned short* L  = &lds[0][0][0];
    unsigned short* Ld = L + wave * 512;         // wave chunk (1 KiB) inside a region

    // ---- fragment ds_read bases (swizzled on the read side) ----
    const int fr = lane & 15;
    const unsigned rofs = (unsigned)(fr * 64 + (((lane >> 4) * 16) ^ (((fr >> 1) & 3) << 4)));
    const unsigned ldsb = lds_addr(L);
    const unsigned aoff = ldsb + (unsigned)(wm * 8192) + rofs;            // A region 0, buf 0
    const unsigned boff = ldsb + 32768u + (unsigned)(wn * 4096) + rofs;   // B region 2, buf 0

    f32x4 acc[8][4] = {};
    bf16x8 a0[4], a1[4], b0[4], b1[4];

    // ---- prologue: T0 fully (8 loads), T1 partial (6 loads); vmcnt(6) completes T0 ----
    STAGE(Ld + 0 * 8192, Ag, 0);                // T0 A h0
    STAGE(Ld + 1 * 8192, Ag, 32);               // T0 A h1
    STAGE(Ld + 2 * 8192, Bg, 0);                // T0 B h0
    STAGE(Ld + 3 * 8192, Bg, 32);               // T0 B h1
    STAGE(Ld + 32768 + 2 * 8192, Bg, 64);       // T1 B h0 -> buf1
    STAGE(Ld + 32768 + 0 * 8192, Ag, 64);       // T1 A h0 -> buf1
    STAGE(Ld + 32768 + 3 * 8192, Bg, 96);       // T1 B h1 -> buf1
    asm volatile("s_waitcnt vmcnt(6)" ::: "memory");
    __builtin_amdgcn_s_barrier();

    // pre-issue reads(T0 p1): A ks0 m0-3 + B ks0 (buf0 is fully retired)
    RD4(a0, aoff, 0);
    RD4(b0, boff, 0);

    for (int T = 0; T < NT8; ++T) {
        const int buf = T & 1;
        const unsigned ab  = aoff + (unsigned)(buf * 65536);
        const unsigned bb  = boff + (unsigned)(buf * 65536);
        const unsigned abn = ab ^ 65536u;               // next buffer bases
        const unsigned bbn = bb ^ 65536u;
        unsigned short* Lc = Ld + buf * 32768;          // current buffer
        unsigned short* Ln = Ld + (buf ^ 1) * 32768;    // next buffer
        const int kn1 = ((T + 1) < NT8 ? (T + 1) : NT8 - 1) * BK8;  // clamp: tail stages garbage, never read
        const int kn2 = ((T + 2) < NT8 ? (T + 2) : NT8 - 1) * BK8;

        // ---------------- phase 1: MFMA(a0,b0) ks0 upper ----------------
        asm volatile("s_waitcnt lgkmcnt(0)" ::: "memory");   // reads(p1) ready
        __builtin_amdgcn_sched_barrier(0);
        STAGE(Ln + 1 * 8192, Ag, kn1 + 32);                  // (T+1) A h1
        RD4(a1, ab, 4096);                                   // reads(p2): A ks0 m4-7
        __builtin_amdgcn_sched_barrier(0);
        __builtin_amdgcn_s_setprio(1);
#pragma unroll
        for (int i = 0; i < 4; ++i)
#pragma unroll
            for (int j = 0; j < 4; ++j)
                acc[i][j] = MFMA_(a0[i], b0[j], acc[i][j]);
        __builtin_amdgcn_s_setprio(0);
        __builtin_amdgcn_s_barrier();

        // ---------------- phase 2: MFMA(a1,b0) ks0 lower ----------------
        asm volatile("s_waitcnt lgkmcnt(0)" ::: "memory");   // reads(p2) ready
        __builtin_amdgcn_sched_barrier(0);
        STAGE(Lc + 2 * 8192, Bg, kn2);                       // (T+2) B h0
        RD4(a0, ab, 16384);                                  // reads(p3): A ks1 m0-3
        RD4(b1, bb, 16384);                                  //            B ks1
        __builtin_amdgcn_sched_barrier(0);
        __builtin_amdgcn_s_setprio(1);
#pragma unroll
        for (int i = 0; i < 4; ++i)
#pragma unroll
            for (int j = 0; j < 4; ++j)
                acc[4 + i][j] = MFMA_(a1[i], b0[j], acc[4 + i][j]);
        __builtin_amdgcn_s_setprio(0);
        __builtin_amdgcn_s_barrier();

        // ---------------- phase 3: MFMA(a0,b1) ks1 upper ----------------
        asm volatile("s_waitcnt lgkmcnt(0)" ::: "memory");   // reads(p3) ready
        __builtin_amdgcn_sched_barrier(0);
        STAGE(Lc + 0 * 8192, Ag, kn2);                       // (T+2) A h0
        RD4(a1, ab, 16384 + 4096);                           // reads(p4): A ks1 m4-7
        __builtin_amdgcn_sched_barrier(0);
        __builtin_amdgcn_s_setprio(1);
#pragma unroll
        for (int i = 0; i < 4; ++i)
#pragma unroll
            for (int j = 0; j < 4; ++j)
                acc[i][j] = MFMA_(a0[i], b1[j], acc[i][j]);
        __builtin_amdgcn_s_setprio(0);
        __builtin_amdgcn_s_barrier();

        // ---------------- phase 4: MFMA(a1,b1) ks1 lower ----------------
        asm volatile("s_waitcnt lgkmcnt(0)" ::: "memory");   // reads(p4) ready
        __builtin_amdgcn_sched_barrier(0);
        STAGE(Lc + 3 * 8192, Bg, kn2 + 32);                  // (T+2) B h1
        asm volatile("s_waitcnt vmcnt(6)" ::: "memory");     // retire ALL of T+1 (next buf readable)
        RD4(a0, abn, 0);                                     // reads(next p1): A ks0 m0-3
        RD4(b0, bbn, 0);                                     //                 B ks0
        __builtin_amdgcn_sched_barrier(0);
        __builtin_amdgcn_s_setprio(1);
#pragma unroll
        for (int i = 0; i < 4; ++i)
#pragma unroll
            for (int j = 0; j < 4; ++j)
                acc[4 + i][j] = MFMA_(a1[i], b1[j], acc[4 + i][j]);
        __builtin_amdgcn_s_setprio(0);
        __builtin_amdgcn_s_barrier();
    }

    // ---- epilogue: NON-TEMPORAL C write (col = lane&15, row = (lane>>4)*4 + reg) ----
    const int cr = (lane >> 4) * 4;
    const int cc = lane & 15;
#pragma unroll
    for (int i = 0; i < 8; ++i) {
#pragma unroll
        for (int j = 0; j < 4; ++j) {
            float* cp = C + (size_t)(m0 + wm * 128 + i * 16 + cr) * N + (n0 + wn * 64 + j * 16 + cc);
            __builtin_nontemporal_store(acc[i][j].x, cp);
            __builtin_nontemporal_store(acc[i][j].y, cp + (size_t)N);
            __builtin_nontemporal_store(acc[i][j].z, cp + (size_t)N * 2);
            __builtin_nontemporal_store(acc[i][j].w, cp + (size_t)N * 3);
        }
    }
}

// ---------- fallback: fused on-the-fly dequant GEMM (if ws too small) ----------
__global__ __launch_bounds__(256, 2) void fused_gemm(const float* __restrict__ X,
                                                     const int* __restrict__ Wp,
                                                     const float* __restrict__ Sc,
                                                     float* __restrict__ C,
                                                     int M, int N) {
    __shared__ __align__(16) unsigned short As[BM * BK];
    __shared__ __align__(16) unsigned short Bs[BN * BK];

    const int tid  = threadIdx.x;
    const int wave = tid >> 6;
    const int lane = tid & 63;
    const int m0 = blockIdx.y * BM;
    const int n0 = blockIdx.x * BN;
    const int wm = (wave >> 1) * 64;
    const int wn = (wave & 1) * 64;

    const int fr = lane & 15;
    const int fk = (lane >> 4) * 8;

    f32x4 acc[4][4] = {};

    for (int k0 = 0; k0 < K_DIM; k0 += BK) {
        __syncthreads();
#pragma unroll
        for (int j = 0; j < 4; ++j) {
            int f = tid + 256 * j;
            int row = f >> 3, c4 = f & 7;
            f32x4 a = *(const f32x4*)(X + (size_t)(m0 + row) * K_DIM + k0 + c4 * 4);
            union { unsigned short u[4]; uint2 q; } o;
            o.u[0] = f2bf(a.x); o.u[1] = f2bf(a.y); o.u[2] = f2bf(a.z); o.u[3] = f2bf(a.w);
            *(uint2*)(As + row * BK + c4 * 4) = o.q;
        }
#pragma unroll
        for (int j = 0; j < 2; ++j) {
            int g = tid + 256 * j;
            int row = g >> 2, c4 = g & 3;
            const int4 v = *(const int4*)(Wp + (size_t)(n0 + row) * (K_DIM / 2) + (k0 >> 1) + c4 * 4);
            float s = Sc[(n0 + row) * N_GROUPS + (k0 >> 7)];
            union { unsigned short u[8]; uint4 q; } o;
            int vv[4] = { v.x, v.y, v.z, v.w };
#pragma unroll
            for (int t = 0; t < 4; ++t) {
                o.u[2 * t]     = f2bf((float)((vv[t] & 15) - 8) * s);
                o.u[2 * t + 1] = f2bf((float)(((vv[t] >> 4) & 15) - 8) * s);
            }
            *(uint4*)(Bs + row * BK + c4 * 8) = o.q;
        }
        __syncthreads();

        bf16x8 af[4], bf[4];
#pragma unroll
        for (int i = 0; i < 4; ++i) {
            af[i] = *(const bf16x8*)(As + (wm + i * 16 + fr) * BK + fk);
            bf[i] = *(const bf16x8*)(Bs + (wn + i * 16 + fr) * BK + fk);
        }
#pragma unroll
        for (int i = 0; i < 4; ++i)
#pragma unroll
            for (int j = 0; j < 4; ++j)
                acc[i][j] = __builtin_amdgcn_mfma_f32_16x16x32_bf16(af[i], bf[j], acc[i][j], 0, 0, 0);
    }

    const int cr = (lane >> 4) * 4;
    const int cc = lane & 15;
#pragma unroll
    for (int i = 0; i < 4; ++i) {
#pragma unroll
        for (int j = 0; j < 4; ++j) {
            float* cp = C + (size_t)(m0 + wm + i * 16 + cr) * N + (n0 + wn + j * 16 + cc);
            cp[0]           = acc[i][j].x;
            cp[(size_t)N]   = acc[i][j].y;
            cp[(size_t)N*2] = acc[i][j].z;
            cp[(size_t)N*3] = acc[i][j].w;
        }
    }
}

extern "C" void kernel_launch(void* const* d_in, const int* in_sizes, int n_in,
                              void* d_out, int out_size, void* d_ws, size_t ws_size,
                              hipStream_t stream) {
    const float* x  = (const float*)d_in[0];
    const int*   wp = (const int*)d_in[1];
    const float* sc = (const float*)d_in[2];
    float* out = (float*)d_out;

    const int M = in_sizes[0] / K_DIM;       // 8192
    const int N = in_sizes[2] / N_GROUPS;    // 11008

    const size_t xb_bytes = (size_t)M * K_DIM * 2;   // 67 MB
    const size_t wd_bytes = (size_t)N * K_DIM * 2;   // 90 MB

    const bool div256 = (M % BM8 == 0) && (N % BN8 == 0);

    if (ws_size >= xb_bytes + wd_bytes && div256) {
        unsigned short* xb = (unsigned short*)d_ws;
        unsigned short* wd = (unsigned short*)((char*)d_ws + xb_bytes);
        int xtot = M * K_DIM;
        cvt_x<<<xtot / (256 * 8), 256, 0, stream>>>(x, xb, xtot);
        int wtot4 = N * (K_DIM / 2) / 4;
        dequant_w<<<(wtot4 + 255) / 256, 256, 0, stream>>>(wp, sc, wd, wtot4);
        gemm8p<<<(M / BM8) * (N / BN8), 512, 0, stream>>>(xb, wd, out, M, N);
    } else {
        dim3 grid(N / BN, M / BM);
        fused_gemm<<<grid, 256, 0, stream>>>(x, wp, sc, out, M, N);
    }
}